// Round 3
// baseline (4022.392 us; speedup 1.0000x reference)
//
#include <hip/hip_runtime.h>
#include <hip/hip_bf16.h>

#define Bn  128
#define Ln  256
#define En  300
#define Hn  128
#define Cn  4
#define Dn  256     // 2H
#define G3n 384     // 3H
#define BLn (Bn * Ln)   // 32768

typedef __hip_bfloat16 bf16;

__device__ __forceinline__ float ldf(const float* p) { return *p; }
__device__ __forceinline__ float ldf(const bf16* p)  { return __bfloat162float(*p); }
__device__ __forceinline__ void stf(float* p, float v) { *p = v; }
__device__ __forceinline__ void stf(bf16* p, float v)  { *p = __float2bfloat16(v); }

// ---------------------------------------------------------------------------
// Tiled GEMM: C[M,N] = A[M,K] * op(W) + bias
//   BT=true : W is (N,K) row-major, C = A * W^T ; BT=false: W is (K,N)
//   GATHER  : A row m is A[gidx[m]*K .. ]  (embedding lookup fused)
//   SM==1   : store transposed-by-256-group: C[(m/256), n, (m%256)]
// ---------------------------------------------------------------------------
template<class AT, class WT, class OT, bool BT, bool GATHER, int SM>
__global__ __launch_bounds__(256)
void gemm_kernel(const AT* __restrict__ A, const WT* __restrict__ W,
                 const WT* __restrict__ bias, OT* __restrict__ Cout,
                 const int* __restrict__ gidx, int M, int N, int K)
{
    __shared__ float As[64][17];
    __shared__ float Bs[16][65];
    const int bm = blockIdx.y * 64, bn = blockIdx.x * 64;
    const int tid = threadIdx.x;
    const int tx = tid & 15, ty = tid >> 4;
    float acc[4][4] = {};
    const int nkt = (K + 15) >> 4;
    for (int kt = 0; kt < nkt; ++kt) {
        const int k0 = kt << 4;
#pragma unroll
        for (int u = 0; u < 4; ++u) {
            int idx = tid + u * 256;
            int m = idx >> 4, k = idx & 15;
            const AT* arow = GATHER ? (A + (size_t)gidx[bm + m] * K)
                                    : (A + (size_t)(bm + m) * K);
            As[m][k] = (k0 + k < K) ? ldf(&arow[k0 + k]) : 0.f;
        }
#pragma unroll
        for (int u = 0; u < 4; ++u) {
            int idx = tid + u * 256;
            if (BT) {
                int n = idx >> 4, k = idx & 15;
                Bs[k][n] = (k0 + k < K) ? ldf(&W[(size_t)(bn + n) * K + k0 + k]) : 0.f;
            } else {
                int k = idx >> 6, n = idx & 63;
                Bs[k][n] = (k0 + k < K) ? ldf(&W[(size_t)(k0 + k) * N + bn + n]) : 0.f;
            }
        }
        __syncthreads();
#pragma unroll
        for (int k = 0; k < 16; ++k) {
            float a[4], b[4];
#pragma unroll
            for (int q = 0; q < 4; ++q) a[q] = As[ty * 4 + q][k];
#pragma unroll
            for (int r = 0; r < 4; ++r) b[r] = Bs[k][tx * 4 + r];
#pragma unroll
            for (int q = 0; q < 4; ++q)
#pragma unroll
                for (int r = 0; r < 4; ++r)
                    acc[q][r] += a[q] * b[r];
        }
        __syncthreads();
    }
#pragma unroll
    for (int q = 0; q < 4; ++q) {
        const int m = bm + ty * 4 + q;
#pragma unroll
        for (int r = 0; r < 4; ++r) {
            const int n = bn + tx * 4 + r;
            float v = acc[q][r];
            if (bias) v += ldf(&bias[n]);
            if (SM == 1)
                stf(&Cout[((size_t)(m >> 8) * N + n) * 256 + (m & 255)], v);
            else
                stf(&Cout[(size_t)m * N + n], v);
        }
    }
}

// ---------------------------------------------------------------------------
// Transpose w_hh (dir,3H,H) -> float whT[layer*2+dir][k][r]
// ---------------------------------------------------------------------------
__global__ void transpose_whh(const float* __restrict__ w0,
                              const float* __restrict__ w1,
                              float* __restrict__ outT)
{
    int layer = blockIdx.y, dir = blockIdx.x;
    const float* src = (layer ? w1 : w0) + (size_t)dir * G3n * Hn;
    float* dst = outT + (size_t)(layer * 2 + dir) * Hn * G3n;
    for (int i = threadIdx.x; i < G3n * Hn; i += blockDim.x) {
        int r = i / Hn, k = i % Hn;
        dst[k * G3n + r] = src[i];
    }
}

// ---------------------------------------------------------------------------
// GRU scan: one block per (batch, dir); 384 threads = one gate row each.
// h in LDS; w_hh^T streamed (coalesced, L2-resident).
// ---------------------------------------------------------------------------
template<class GxT>
__global__ __launch_bounds__(384)
void gru_scan(const GxT* __restrict__ gx, const float* __restrict__ whT,
              const float* __restrict__ b_hh, float* __restrict__ out)
{
    const int b = blockIdx.x, dir = blockIdx.y;
    const int r = threadIdx.x;
    __shared__ float h_sh[Hn];
    __shared__ float pre_rz[2 * Hn];
    __shared__ float gxn[Hn], ghn[Hn];
    const float* wT = whT + (size_t)dir * Hn * G3n;
    const float bh = b_hh[dir * G3n + r];
    if (r < Hn) h_sh[r] = 0.f;
    __syncthreads();
    for (int s = 0; s < Ln; ++s) {
        const int t = dir ? (Ln - 1 - s) : s;
        float acc = 0.f;
#pragma unroll 8
        for (int k = 0; k < Hn; ++k)
            acc += wT[k * G3n + r] * h_sh[k];
        acc += bh;
        const float gxv = ldf(&gx[((size_t)b * Ln + t) * 768 + dir * G3n + r]);
        if (r < 2 * Hn) pre_rz[r] = gxv + acc;
        else { gxn[r - 2 * Hn] = gxv; ghn[r - 2 * Hn] = acc; }
        __syncthreads();
        if (r < Hn) {
            const float rr = 1.f / (1.f + expf(-pre_rz[r]));
            const float zz = 1.f / (1.f + expf(-pre_rz[Hn + r]));
            const float nn = tanhf(gxn[r] + rr * ghn[r]);
            const float hnew = (1.f - zz) * nn + zz * h_sh[r];
            h_sh[r] = hnew;
            out[((size_t)b * Ln + t) * Dn + dir * Hn + r] = hnew;
        }
        __syncthreads();
    }
}

// ---------------------------------------------------------------------------
// s[b,i] = sum_j tanh( x[b,i,:]·matc[b,j,:] + att_b[c] )  (single channel c)
// ---------------------------------------------------------------------------
__global__ __launch_bounds__(256)
void attn_score_kernel(const float* __restrict__ x, const float* __restrict__ matc,
                       const float* __restrict__ attb, int c, float* __restrict__ sout)
{
    const int it = blockIdx.x, b = blockIdx.y;
    const float* A  = x    + (size_t)b * Ln * Dn;
    const float* Bm = matc + (size_t)b * Ln * Dn;
    __shared__ float As[64][17];
    __shared__ float Bs[64][17];
    __shared__ float red[64][16];
    const int tid = threadIdx.x, tx = tid & 15, ty = tid >> 4;
    const float bc = attb[c];
    float ssum[4] = {0.f, 0.f, 0.f, 0.f};
    for (int jt = 0; jt < 4; ++jt) {
        float acc[4][4] = {};
        for (int kt = 0; kt < 16; ++kt) {
            const int k0 = kt << 4;
#pragma unroll
            for (int u = 0; u < 4; ++u) {
                int idx = tid + u * 256;
                int m = idx >> 4, k = idx & 15;
                As[m][k] = A[(size_t)(it * 64 + m) * Dn + k0 + k];
                Bs[m][k] = Bm[(size_t)(jt * 64 + m) * Dn + k0 + k];
            }
            __syncthreads();
#pragma unroll
            for (int k = 0; k < 16; ++k) {
                float a[4], bb[4];
#pragma unroll
                for (int q = 0; q < 4; ++q) a[q] = As[ty * 4 + q][k];
#pragma unroll
                for (int r = 0; r < 4; ++r) bb[r] = Bs[tx * 4 + r][k];
#pragma unroll
                for (int q = 0; q < 4; ++q)
#pragma unroll
                    for (int r = 0; r < 4; ++r)
                        acc[q][r] += a[q] * bb[r];
            }
            __syncthreads();
        }
#pragma unroll
        for (int q = 0; q < 4; ++q)
#pragma unroll
            for (int r = 0; r < 4; ++r)
                ssum[q] += tanhf(acc[q][r] + bc);
    }
#pragma unroll
    for (int q = 0; q < 4; ++q) red[ty * 4 + q][tx] = ssum[q];
    __syncthreads();
    if (tid < 64) {
        float tot = 0.f;
#pragma unroll
        for (int u = 0; u < 16; ++u) tot += red[tid][u];
        sout[b * Ln + it * 64 + tid] = tot;
    }
}

// ---------------------------------------------------------------------------
// aa_logit[c,m] = sum_e sigmoid((x[m]·wv2[c])[e] + bv[c,e]) * wv1[c,e]
// ---------------------------------------------------------------------------
__global__ __launch_bounds__(256)
void attn_vec_kernel(const float* __restrict__ x, const float* __restrict__ wv2,
                     const float* __restrict__ bv, const float* __restrict__ wv1,
                     float* __restrict__ al)
{
    const int bm = blockIdx.x * 64, c = blockIdx.y;
    const float* W = wv2 + (size_t)c * Dn * Dn;
    __shared__ float As[64][17];
    __shared__ float Bs[16][65];
    __shared__ float red[64][16];
    const int tid = threadIdx.x, tx = tid & 15, ty = tid >> 4;
    float ssum[4] = {0.f, 0.f, 0.f, 0.f};
    for (int et = 0; et < 4; ++et) {
        float acc[4][4] = {};
        for (int kt = 0; kt < 16; ++kt) {
            const int k0 = kt << 4;
#pragma unroll
            for (int u = 0; u < 4; ++u) {
                int idx = tid + u * 256;
                int m = idx >> 4, k = idx & 15;
                As[m][k] = x[(size_t)(bm + m) * Dn + k0 + k];
            }
#pragma unroll
            for (int u = 0; u < 4; ++u) {
                int idx = tid + u * 256;
                int k = idx >> 6, n = idx & 63;
                Bs[k][n] = W[(size_t)(k0 + k) * Dn + et * 64 + n];
            }
            __syncthreads();
#pragma unroll
            for (int k = 0; k < 16; ++k) {
                float a[4], b[4];
#pragma unroll
                for (int q = 0; q < 4; ++q) a[q] = As[ty * 4 + q][k];
#pragma unroll
                for (int r = 0; r < 4; ++r) b[r] = Bs[k][tx * 4 + r];
#pragma unroll
                for (int q = 0; q < 4; ++q)
#pragma unroll
                    for (int r = 0; r < 4; ++r)
                        acc[q][r] += a[q] * b[r];
            }
            __syncthreads();
        }
#pragma unroll
        for (int q = 0; q < 4; ++q)
#pragma unroll
            for (int r = 0; r < 4; ++r) {
                const int e = et * 64 + tx * 4 + r;
                const float sg = 1.f / (1.f + expf(-(acc[q][r] + bv[c * Dn + e])));
                ssum[q] += sg * wv1[c * Dn + e];
            }
    }
#pragma unroll
    for (int q = 0; q < 4; ++q) red[ty * 4 + q][tx] = ssum[q];
    __syncthreads();
    if (tid < 64) {
        float tot = 0.f;
#pragma unroll
        for (int u = 0; u < 16; ++u) tot += red[tid][u];
        al[(size_t)c * BLn + bm + tid] = tot;
    }
}

__global__ void softmax256(const float* __restrict__ in, float* __restrict__ out)
{
    __shared__ float red[256];
    const int row = blockIdx.x, t = threadIdx.x;
    const float v = in[(size_t)row * 256 + t];
    red[t] = v; __syncthreads();
    for (int off = 128; off; off >>= 1) {
        if (t < off) red[t] = fmaxf(red[t], red[t + off]);
        __syncthreads();
    }
    const float mx = red[0]; __syncthreads();
    const float e = expf(v - mx);
    red[t] = e; __syncthreads();
    for (int off = 128; off; off >>= 1) {
        if (t < off) red[t] += red[t + off];
        __syncthreads();
    }
    out[(size_t)row * 256 + t] = e / red[0];
}

// new[c,b,d] = sum_l aa[c,b,l] * x[b,l,d]
__global__ void weighted_sum_kernel(const float* __restrict__ aa,
                                    const float* __restrict__ x,
                                    float* __restrict__ outnew)
{
    const int b = blockIdx.x, c = blockIdx.y, d = threadIdx.x;
    __shared__ float w[Ln];
    w[d] = aa[((size_t)c * Bn + b) * Ln + d];
    __syncthreads();
    float acc = 0.f;
    for (int l = 0; l < Ln; ++l)
        acc += w[l] * x[((size_t)b * Ln + l) * Dn + d];
    outnew[((size_t)c * Bn + b) * Dn + d] = acc;
}

// ---------------------------------------------------------------------------
// Pack all conv filter rows (216) into a 256x256 fp32 matrix (rows 216+ zero).
// Row order: f-major, then (o*4+c)*fs+kh == natural flat order of conv_w.
// ---------------------------------------------------------------------------
__global__ void wpack_fill(const float* __restrict__ w0, const float* __restrict__ w1,
                           const float* __restrict__ w2, const float* __restrict__ w3,
                           float* __restrict__ wp)
{
    const int f = blockIdx.x;
    if (f < 4) {
        const int cnt[4]  = {4096, 9216, 16384, 25600};
        const int boff[4] = {0, 4096, 13312, 29696};
        const float* src = f == 0 ? w0 : f == 1 ? w1 : f == 2 ? w2 : w3;
        for (int i = threadIdx.x; i < cnt[f]; i += blockDim.x)
            wp[boff[f] + i] = src[i];
    } else {
        for (int i = threadIdx.x; i < 65536 - 55296; i += blockDim.x)
            wp[55296 + i] = 0.f;
    }
}

// nwd[b,row] = dot(new[c_of_row, b, :], wpack[row, :])
__global__ __launch_bounds__(256)
void nwd_kernel(const float* __restrict__ nw, const float* __restrict__ wp,
                float* __restrict__ nwd)
{
    const int b = blockIdx.x;
    __shared__ float ns[4][256];
    for (int i = threadIdx.x; i < 1024; i += 256)
        ns[i >> 8][i & 255] = nw[((size_t)((i >> 8) * Bn + b) << 8) + (i & 255)];
    __syncthreads();
    const int row = threadIdx.x;
    if (row < 216) {
        int f, base;
        if (row < 16)       { f = 0; base = 0; }
        else if (row < 52)  { f = 1; base = 16; }
        else if (row < 116) { f = 2; base = 52; }
        else                { f = 3; base = 116; }
        const int fs = f + 2, local = row - base;
        const int c = (local / fs) & 3;
        const float* wr = wp + (size_t)row * 256;
        float acc = 0.f;
        for (int k = 0; k < 256; ++k) acc += ns[c][k] * wr[k];
        nwd[b * 256 + row] = acc;
    }
}

// ---------------------------------------------------------------------------
// Conv+ReLU+maxpool via decomposition:
//  y[b,o,i] = bias[o] + sum_{c,kh} nwd[b,row] + sum_{c,kh} a[c,b,i+kh]*xwT[b,row,i+kh]
// ---------------------------------------------------------------------------
__global__ __launch_bounds__(256)
void conv_combine(const float* __restrict__ xwT, const float* __restrict__ a,
                  const float* __restrict__ nwd, const float* __restrict__ cb,
                  float* __restrict__ pool, int fs, int base, int poff)
{
    const int b = blockIdx.x, tid = threadIdx.x;
    __shared__ float ash[4][256];
    __shared__ float basev[5];
    __shared__ float red[256];
    for (int i = tid; i < 1024; i += 256)
        ash[i >> 8][i & 255] = a[((size_t)((i >> 8) * Bn + b) << 8) + (i & 255)];
    if (tid < fs) {
        float s = cb[tid];
        for (int c = 0; c < 4; ++c)
            for (int kh = 0; kh < fs; ++kh)
                s += nwd[b * 256 + base + (tid * 4 + c) * fs + kh];
        basev[tid] = s;
    }
    __syncthreads();
    const int ni = Ln - fs + 1;
    const float* xb = xwT + ((size_t)b << 16);
    for (int o = 0; o < fs; ++o) {
        float best = 0.f;
        if (tid < ni) {
            float acc = basev[o];
            for (int c = 0; c < 4; ++c)
                for (int kh = 0; kh < fs; ++kh) {
                    const int row = base + (o * 4 + c) * fs + kh;
                    acc += ash[c][tid + kh] * xb[(row << 8) + tid + kh];
                }
            best = fmaxf(acc, 0.f);
        }
        red[tid] = best; __syncthreads();
        for (int off = 128; off; off >>= 1) {
            if (tid < off) red[tid] = fmaxf(red[tid], red[tid + off]);
            __syncthreads();
        }
        if (tid == 0) pool[b * 14 + poff + o] = red[0];
        __syncthreads();
    }
}

__global__ void fc_kernel(const float* __restrict__ pool, const float* __restrict__ fw,
                          const float* __restrict__ fb, float* __restrict__ out)
{
    const int i = threadIdx.x;           // 256 = B*OUT
    const int b = i >> 1, o = i & 1;
    float acc = fb[o];
#pragma unroll
    for (int f = 0; f < 14; ++f) acc += pool[b * 14 + f] * fw[o * 14 + f];
    out[i] = acc;
}

// ---------------------------------------------------------------------------
extern "C" void kernel_launch(void* const* d_in, const int* in_sizes, int n_in,
                              void* d_out, int out_size, void* d_ws, size_t ws_size,
                              hipStream_t stream)
{
    const int*   utt    = (const int*)  d_in[0];
    const float* emb    = (const float*)d_in[2];
    const float* w_ih0  = (const float*)d_in[3];
    const float* w_hh0  = (const float*)d_in[4];
    const float* b_ih0  = (const float*)d_in[5];
    const float* b_hh0  = (const float*)d_in[6];
    const float* w_ih1  = (const float*)d_in[7];
    const float* w_hh1  = (const float*)d_in[8];
    const float* b_ih1  = (const float*)d_in[9];
    const float* b_hh1  = (const float*)d_in[10];
    const float* att_w  = (const float*)d_in[11];
    const float* att_b  = (const float*)d_in[12];
    const float* att_wv2= (const float*)d_in[13];
    const float* att_bv = (const float*)d_in[14];
    const float* att_wv1= (const float*)d_in[15];
    const float* fc_w   = (const float*)d_in[16];
    const float* fc_b   = (const float*)d_in[17];
    const float* cw[4] = {(const float*)d_in[18], (const float*)d_in[20],
                          (const float*)d_in[22], (const float*)d_in[24]};
    const float* cb[4] = {(const float*)d_in[19], (const float*)d_in[21],
                          (const float*)d_in[23], (const float*)d_in[25]};

    float* ws = (float*)d_ws;
    // fat layout: fp32 gx staging (needs 171.6 MB); slim: bf16 gx (121.3 MB,
    // proven in-bounds by round 2's clean run)
    const bool fat = ws_size >= (size_t)42895104 * 4;
    const size_t oH1 = fat ? 25165824u : 12582912u;   // gx region in f32 slots
    float* H1   = ws + oH1;            // 8,388,608 f ; later aliased as MATc
    float* H2   = H1 + 8388608;        // 8,388,608 f
    float* WHT  = H2 + 8388608;        //   196,608 f
    float* WP   = WHT + 196608;        //    65,536 f
    float* S    = WP + 65536;          //   131,072 f
    float* Aa   = S + 131072;
    float* AL   = Aa + 131072;
    float* AAa  = AL + 131072;
    float* NEW_ = AAa + 131072;
    float* NWD  = NEW_ + 131072;       //    32,768 f
    float* POOL = NWD + 32768;         //     1,792 f
    float* MATc = H1;                  // alias (H1 dead after layer-1 gemm)
    float* XWT  = ws;                  // alias (gx dead after layer-1 scan)

    transpose_whh<<<dim3(2, 2), 256, 0, stream>>>(w_hh0, w_hh1, WHT);

    if (fat) {
        float* GX = ws;
        gemm_kernel<float, float, float, true, true, 0><<<dim3(12, 512), 256, 0, stream>>>(
            emb, w_ih0, b_ih0, GX, utt, BLn, 768, En);
        gru_scan<float><<<dim3(Bn, 2), 384, 0, stream>>>(GX, WHT, b_hh0, H1);
        gemm_kernel<float, float, float, true, false, 0><<<dim3(12, 512), 256, 0, stream>>>(
            H1, w_ih1, b_ih1, GX, nullptr, BLn, 768, Dn);
        gru_scan<float><<<dim3(Bn, 2), 384, 0, stream>>>(GX, WHT + 2 * Hn * G3n, b_hh1, H2);
    } else {
        bf16* GX = (bf16*)ws;
        gemm_kernel<float, float, bf16, true, true, 0><<<dim3(12, 512), 256, 0, stream>>>(
            emb, w_ih0, b_ih0, GX, utt, BLn, 768, En);
        gru_scan<bf16><<<dim3(Bn, 2), 384, 0, stream>>>(GX, WHT, b_hh0, H1);
        gemm_kernel<float, float, bf16, true, false, 0><<<dim3(12, 512), 256, 0, stream>>>(
            H1, w_ih1, b_ih1, GX, nullptr, BLn, 768, Dn);
        gru_scan<bf16><<<dim3(Bn, 2), 384, 0, stream>>>(GX, WHT + 2 * Hn * G3n, b_hh1, H2);
    }

    // attention: per channel, mat_c = x @ att_w[c] (reusing MATc), then scores
    for (int c = 0; c < 4; ++c) {
        gemm_kernel<float, float, float, false, false, 0><<<dim3(4, 512), 256, 0, stream>>>(
            H2, att_w + (size_t)c * Dn * Dn, (const float*)nullptr, MATc, nullptr, BLn, Dn, Dn);
        attn_score_kernel<<<dim3(4, Bn), 256, 0, stream>>>(H2, MATc, att_b, c, S + (size_t)c * 32768);
    }
    softmax256<<<Cn * Bn, 256, 0, stream>>>(S, Aa);

    attn_vec_kernel<<<dim3(BLn / 64, Cn), 256, 0, stream>>>(H2, att_wv2, att_bv, att_wv1, AL);
    softmax256<<<Cn * Bn, 256, 0, stream>>>(AL, AAa);
    weighted_sum_kernel<<<dim3(Bn, Cn), 256, 0, stream>>>(AAa, H2, NEW_);

    // conv stage via xw GEMM decomposition (Cf never materialized)
    wpack_fill<<<5, 256, 0, stream>>>(cw[0], cw[1], cw[2], cw[3], WP);
    gemm_kernel<float, float, float, true, false, 1><<<dim3(4, 512), 256, 0, stream>>>(
        H2, WP, (const float*)nullptr, XWT, nullptr, BLn, 256, 256);
    nwd_kernel<<<Bn, 256, 0, stream>>>(NEW_, WP, NWD);

    const int baserow[4] = {0, 16, 52, 116};
    const int poff[4]    = {0, 2, 5, 9};
    for (int f = 0; f < 4; ++f)
        conv_combine<<<Bn, 256, 0, stream>>>(XWT, Aa, NWD, cb[f], POOL, f + 2, baserow[f], poff[f]);

    fc_kernel<<<1, 256, 0, stream>>>(POOL, fc_w, fc_b, (float*)d_out);
}

// Round 4
// 2814.243 us; speedup vs baseline: 1.4293x; 1.4293x over previous
//
#include <hip/hip_runtime.h>
#include <hip/hip_bf16.h>

#define Bn  128
#define Ln  256
#define En  300
#define Hn  128
#define Cn  4
#define Dn  256     // 2H
#define G3n 384     // 3H
#define BLn (Bn * Ln)   // 32768

typedef __hip_bfloat16 bf16;

__device__ __forceinline__ float ldf(const float* p) { return *p; }
__device__ __forceinline__ float ldf(const bf16* p)  { return __bfloat162float(*p); }
__device__ __forceinline__ void stf(float* p, float v) { *p = v; }
__device__ __forceinline__ void stf(bf16* p, float v)  { *p = __float2bfloat16(v); }

// ---------------------------------------------------------------------------
// Tiled GEMM: C[M,N] = A[M,K] * op(W) + bias
//   BT=true : W is (N,K) row-major, C = A * W^T ; BT=false: W is (K,N)
//   GATHER  : A row m is A[gidx[m]*K .. ]  (embedding lookup fused)
//   SM==1   : store transposed-by-256-group: C[(m/256), n, (m%256)]
// ---------------------------------------------------------------------------
template<class AT, class WT, class OT, bool BT, bool GATHER, int SM>
__global__ __launch_bounds__(256)
void gemm_kernel(const AT* __restrict__ A, const WT* __restrict__ W,
                 const WT* __restrict__ bias, OT* __restrict__ Cout,
                 const int* __restrict__ gidx, int M, int N, int K)
{
    __shared__ float As[64][17];
    __shared__ float Bs[16][65];
    const int bm = blockIdx.y * 64, bn = blockIdx.x * 64;
    const int tid = threadIdx.x;
    const int tx = tid & 15, ty = tid >> 4;
    float acc[4][4] = {};
    const int nkt = (K + 15) >> 4;
    for (int kt = 0; kt < nkt; ++kt) {
        const int k0 = kt << 4;
#pragma unroll
        for (int u = 0; u < 4; ++u) {
            int idx = tid + u * 256;
            int m = idx >> 4, k = idx & 15;
            const AT* arow = GATHER ? (A + (size_t)gidx[bm + m] * K)
                                    : (A + (size_t)(bm + m) * K);
            As[m][k] = (k0 + k < K) ? ldf(&arow[k0 + k]) : 0.f;
        }
#pragma unroll
        for (int u = 0; u < 4; ++u) {
            int idx = tid + u * 256;
            if (BT) {
                int n = idx >> 4, k = idx & 15;
                Bs[k][n] = (k0 + k < K) ? ldf(&W[(size_t)(bn + n) * K + k0 + k]) : 0.f;
            } else {
                int k = idx >> 6, n = idx & 63;
                Bs[k][n] = (k0 + k < K) ? ldf(&W[(size_t)(k0 + k) * N + bn + n]) : 0.f;
            }
        }
        __syncthreads();
#pragma unroll
        for (int k = 0; k < 16; ++k) {
            float a[4], b[4];
#pragma unroll
            for (int q = 0; q < 4; ++q) a[q] = As[ty * 4 + q][k];
#pragma unroll
            for (int r = 0; r < 4; ++r) b[r] = Bs[k][tx * 4 + r];
#pragma unroll
            for (int q = 0; q < 4; ++q)
#pragma unroll
                for (int r = 0; r < 4; ++r)
                    acc[q][r] += a[q] * b[r];
        }
        __syncthreads();
    }
#pragma unroll
    for (int q = 0; q < 4; ++q) {
        const int m = bm + ty * 4 + q;
#pragma unroll
        for (int r = 0; r < 4; ++r) {
            const int n = bn + tx * 4 + r;
            float v = acc[q][r];
            if (bias) v += ldf(&bias[n]);
            if (SM == 1)
                stf(&Cout[((size_t)(m >> 8) * N + n) * 256 + (m & 255)], v);
            else
                stf(&Cout[(size_t)m * N + n], v);
        }
    }
}

// ---------------------------------------------------------------------------
// GRU scan, register-resident weights. One block per (batch, dir); 384
// threads = one gate row each. Thread r keeps w_hh[dir][r][0:128] in 128
// VGPRs (loaded once; L2 weight re-reads eliminated -- round-3 profile
// showed the old version saturating L2 at ~34 TB/s on weight streams).
// h broadcast via LDS (same-address reads are conflict-free). gx software-
// prefetched 2 steps ahead to hide HBM latency under the dot product.
// ---------------------------------------------------------------------------
template<class GxT>
__global__ __launch_bounds__(384, 1)
void gru_scan(const GxT* __restrict__ gx, const float* __restrict__ w_hh,
              const float* __restrict__ b_hh, float* __restrict__ out)
{
    const int b = blockIdx.x, dir = blockIdx.y;
    const int r = threadIdx.x;
    __shared__ __align__(16) float h_sh[Hn];
    __shared__ float pre_rz[2 * Hn];
    __shared__ float gxn[Hn], ghn[Hn];

    // one-time: this thread's weight row into registers (natural input layout)
    const float* wrow = w_hh + ((size_t)dir * G3n + r) * Hn;
    float wreg[Hn];
#pragma unroll
    for (int j = 0; j < Hn / 4; ++j)
        *(float4*)(wreg + 4 * j) = *(const float4*)(wrow + 4 * j);
    const float bh = b_hh[dir * G3n + r];

    if (r < Hn) h_sh[r] = 0.f;
    __syncthreads();

    // gx stream index for step s: t = dir ? L-1-s : s
    const size_t gbase = (size_t)b * Ln * 768 + dir * G3n + r;
    const long   gstep = dir ? -768 : 768;
    const size_t g0    = dir ? (gbase + (size_t)(Ln - 1) * 768) : gbase;

    float gcur = ldf(&gx[g0]);
    float gnx  = ldf(&gx[g0 + gstep]);

    for (int s = 0; s < Ln; ++s) {
        const int t = dir ? (Ln - 1 - s) : s;
        // prefetch step s+2
        float gn2 = 0.f;
        if (s + 2 < Ln) gn2 = ldf(&gx[g0 + (long)(s + 2) * gstep]);

        float a0 = 0.f, a1 = 0.f, a2 = 0.f, a3 = 0.f;
#pragma unroll
        for (int j = 0; j < Hn / 4; ++j) {
            const float4 hv = *(const float4*)(h_sh + 4 * j);
            a0 = fmaf(wreg[4 * j + 0], hv.x, a0);
            a1 = fmaf(wreg[4 * j + 1], hv.y, a1);
            a2 = fmaf(wreg[4 * j + 2], hv.z, a2);
            a3 = fmaf(wreg[4 * j + 3], hv.w, a3);
        }
        const float acc = (a0 + a1) + (a2 + a3) + bh;
        const float gxv = gcur;
        if (r < 2 * Hn) pre_rz[r] = gxv + acc;
        else { gxn[r - 2 * Hn] = gxv; ghn[r - 2 * Hn] = acc; }
        __syncthreads();
        if (r < Hn) {
            const float rr = 1.f / (1.f + expf(-pre_rz[r]));
            const float zz = 1.f / (1.f + expf(-pre_rz[Hn + r]));
            const float nn = tanhf(gxn[r] + rr * ghn[r]);
            const float hnew = (1.f - zz) * nn + zz * h_sh[r];
            h_sh[r] = hnew;
            out[((size_t)b * Ln + t) * Dn + dir * Hn + r] = hnew;
        }
        __syncthreads();
        gcur = gnx;
        gnx  = gn2;
    }
}

// ---------------------------------------------------------------------------
// s[b,i] = sum_j tanh( x[b,i,:]·matc[b,j,:] + att_b[c] )  (single channel c)
// ---------------------------------------------------------------------------
__global__ __launch_bounds__(256)
void attn_score_kernel(const float* __restrict__ x, const float* __restrict__ matc,
                       const float* __restrict__ attb, int c, float* __restrict__ sout)
{
    const int it = blockIdx.x, b = blockIdx.y;
    const float* A  = x    + (size_t)b * Ln * Dn;
    const float* Bm = matc + (size_t)b * Ln * Dn;
    __shared__ float As[64][17];
    __shared__ float Bs[64][17];
    __shared__ float red[64][16];
    const int tid = threadIdx.x, tx = tid & 15, ty = tid >> 4;
    const float bc = attb[c];
    float ssum[4] = {0.f, 0.f, 0.f, 0.f};
    for (int jt = 0; jt < 4; ++jt) {
        float acc[4][4] = {};
        for (int kt = 0; kt < 16; ++kt) {
            const int k0 = kt << 4;
#pragma unroll
            for (int u = 0; u < 4; ++u) {
                int idx = tid + u * 256;
                int m = idx >> 4, k = idx & 15;
                As[m][k] = A[(size_t)(it * 64 + m) * Dn + k0 + k];
                Bs[m][k] = Bm[(size_t)(jt * 64 + m) * Dn + k0 + k];
            }
            __syncthreads();
#pragma unroll
            for (int k = 0; k < 16; ++k) {
                float a[4], bb[4];
#pragma unroll
                for (int q = 0; q < 4; ++q) a[q] = As[ty * 4 + q][k];
#pragma unroll
                for (int r = 0; r < 4; ++r) bb[r] = Bs[tx * 4 + r][k];
#pragma unroll
                for (int q = 0; q < 4; ++q)
#pragma unroll
                    for (int r = 0; r < 4; ++r)
                        acc[q][r] += a[q] * bb[r];
            }
            __syncthreads();
        }
#pragma unroll
        for (int q = 0; q < 4; ++q)
#pragma unroll
            for (int r = 0; r < 4; ++r)
                ssum[q] += tanhf(acc[q][r] + bc);
    }
#pragma unroll
    for (int q = 0; q < 4; ++q) red[ty * 4 + q][tx] = ssum[q];
    __syncthreads();
    if (tid < 64) {
        float tot = 0.f;
#pragma unroll
        for (int u = 0; u < 16; ++u) tot += red[tid][u];
        sout[b * Ln + it * 64 + tid] = tot;
    }
}

// ---------------------------------------------------------------------------
// aa_logit[c,m] = sum_e sigmoid((x[m]·wv2[c])[e] + bv[c,e]) * wv1[c,e]
// ---------------------------------------------------------------------------
__global__ __launch_bounds__(256)
void attn_vec_kernel(const float* __restrict__ x, const float* __restrict__ wv2,
                     const float* __restrict__ bv, const float* __restrict__ wv1,
                     float* __restrict__ al)
{
    const int bm = blockIdx.x * 64, c = blockIdx.y;
    const float* W = wv2 + (size_t)c * Dn * Dn;
    __shared__ float As[64][17];
    __shared__ float Bs[16][65];
    __shared__ float red[64][16];
    const int tid = threadIdx.x, tx = tid & 15, ty = tid >> 4;
    float ssum[4] = {0.f, 0.f, 0.f, 0.f};
    for (int et = 0; et < 4; ++et) {
        float acc[4][4] = {};
        for (int kt = 0; kt < 16; ++kt) {
            const int k0 = kt << 4;
#pragma unroll
            for (int u = 0; u < 4; ++u) {
                int idx = tid + u * 256;
                int m = idx >> 4, k = idx & 15;
                As[m][k] = x[(size_t)(bm + m) * Dn + k0 + k];
            }
#pragma unroll
            for (int u = 0; u < 4; ++u) {
                int idx = tid + u * 256;
                int k = idx >> 6, n = idx & 63;
                Bs[k][n] = W[(size_t)(k0 + k) * Dn + et * 64 + n];
            }
            __syncthreads();
#pragma unroll
            for (int k = 0; k < 16; ++k) {
                float a[4], b[4];
#pragma unroll
                for (int q = 0; q < 4; ++q) a[q] = As[ty * 4 + q][k];
#pragma unroll
                for (int r = 0; r < 4; ++r) b[r] = Bs[k][tx * 4 + r];
#pragma unroll
                for (int q = 0; q < 4; ++q)
#pragma unroll
                    for (int r = 0; r < 4; ++r)
                        acc[q][r] += a[q] * b[r];
            }
            __syncthreads();
        }
#pragma unroll
        for (int q = 0; q < 4; ++q)
#pragma unroll
            for (int r = 0; r < 4; ++r) {
                const int e = et * 64 + tx * 4 + r;
                const float sg = 1.f / (1.f + expf(-(acc[q][r] + bv[c * Dn + e])));
                ssum[q] += sg * wv1[c * Dn + e];
            }
    }
#pragma unroll
    for (int q = 0; q < 4; ++q) red[ty * 4 + q][tx] = ssum[q];
    __syncthreads();
    if (tid < 64) {
        float tot = 0.f;
#pragma unroll
        for (int u = 0; u < 16; ++u) tot += red[tid][u];
        al[(size_t)c * BLn + bm + tid] = tot;
    }
}

__global__ void softmax256(const float* __restrict__ in, float* __restrict__ out)
{
    __shared__ float red[256];
    const int row = blockIdx.x, t = threadIdx.x;
    const float v = in[(size_t)row * 256 + t];
    red[t] = v; __syncthreads();
    for (int off = 128; off; off >>= 1) {
        if (t < off) red[t] = fmaxf(red[t], red[t + off]);
        __syncthreads();
    }
    const float mx = red[0]; __syncthreads();
    const float e = expf(v - mx);
    red[t] = e; __syncthreads();
    for (int off = 128; off; off >>= 1) {
        if (t < off) red[t] += red[t + off];
        __syncthreads();
    }
    out[(size_t)row * 256 + t] = e / red[0];
}

// new[c,b,d] = sum_l aa[c,b,l] * x[b,l,d]
__global__ void weighted_sum_kernel(const float* __restrict__ aa,
                                    const float* __restrict__ x,
                                    float* __restrict__ outnew)
{
    const int b = blockIdx.x, c = blockIdx.y, d = threadIdx.x;
    __shared__ float w[Ln];
    w[d] = aa[((size_t)c * Bn + b) * Ln + d];
    __syncthreads();
    float acc = 0.f;
    for (int l = 0; l < Ln; ++l)
        acc += w[l] * x[((size_t)b * Ln + l) * Dn + d];
    outnew[((size_t)c * Bn + b) * Dn + d] = acc;
}

// ---------------------------------------------------------------------------
// Pack all conv filter rows (216) into a 256x256 fp32 matrix (rows 216+ zero).
// Row order: f-major, then (o*4+c)*fs+kh == natural flat order of conv_w.
// ---------------------------------------------------------------------------
__global__ void wpack_fill(const float* __restrict__ w0, const float* __restrict__ w1,
                           const float* __restrict__ w2, const float* __restrict__ w3,
                           float* __restrict__ wp)
{
    const int f = blockIdx.x;
    if (f < 4) {
        const int cnt[4]  = {4096, 9216, 16384, 25600};
        const int boff[4] = {0, 4096, 13312, 29696};
        const float* src = f == 0 ? w0 : f == 1 ? w1 : f == 2 ? w2 : w3;
        for (int i = threadIdx.x; i < cnt[f]; i += blockDim.x)
            wp[boff[f] + i] = src[i];
    } else {
        for (int i = threadIdx.x; i < 65536 - 55296; i += blockDim.x)
            wp[55296 + i] = 0.f;
    }
}

// nwd[b,row] = dot(new[c_of_row, b, :], wpack[row, :])
__global__ __launch_bounds__(256)
void nwd_kernel(const float* __restrict__ nw, const float* __restrict__ wp,
                float* __restrict__ nwd)
{
    const int b = blockIdx.x;
    __shared__ float ns[4][256];
    for (int i = threadIdx.x; i < 1024; i += 256)
        ns[i >> 8][i & 255] = nw[((size_t)((i >> 8) * Bn + b) << 8) + (i & 255)];
    __syncthreads();
    const int row = threadIdx.x;
    if (row < 216) {
        int f, base;
        if (row < 16)       { f = 0; base = 0; }
        else if (row < 52)  { f = 1; base = 16; }
        else if (row < 116) { f = 2; base = 52; }
        else                { f = 3; base = 116; }
        const int fs = f + 2, local = row - base;
        const int c = (local / fs) & 3;
        const float* wr = wp + (size_t)row * 256;
        float acc = 0.f;
        for (int k = 0; k < 256; ++k) acc += ns[c][k] * wr[k];
        nwd[b * 256 + row] = acc;
    }
}

// ---------------------------------------------------------------------------
// Conv+ReLU+maxpool via decomposition:
//  y[b,o,i] = bias[o] + sum_{c,kh} nwd[b,row] + sum_{c,kh} a[c,b,i+kh]*xwT[b,row,i+kh]
// ---------------------------------------------------------------------------
__global__ __launch_bounds__(256)
void conv_combine(const float* __restrict__ xwT, const float* __restrict__ a,
                  const float* __restrict__ nwd, const float* __restrict__ cb,
                  float* __restrict__ pool, int fs, int base, int poff)
{
    const int b = blockIdx.x, tid = threadIdx.x;
    __shared__ float ash[4][256];
    __shared__ float basev[5];
    __shared__ float red[256];
    for (int i = tid; i < 1024; i += 256)
        ash[i >> 8][i & 255] = a[((size_t)((i >> 8) * Bn + b) << 8) + (i & 255)];
    if (tid < fs) {
        float s = cb[tid];
        for (int c = 0; c < 4; ++c)
            for (int kh = 0; kh < fs; ++kh)
                s += nwd[b * 256 + base + (tid * 4 + c) * fs + kh];
        basev[tid] = s;
    }
    __syncthreads();
    const int ni = Ln - fs + 1;
    const float* xb = xwT + ((size_t)b << 16);
    for (int o = 0; o < fs; ++o) {
        float best = 0.f;
        if (tid < ni) {
            float acc = basev[o];
            for (int c = 0; c < 4; ++c)
                for (int kh = 0; kh < fs; ++kh) {
                    const int row = base + (o * 4 + c) * fs + kh;
                    acc += ash[c][tid + kh] * xb[(row << 8) + tid + kh];
                }
            best = fmaxf(acc, 0.f);
        }
        red[tid] = best; __syncthreads();
        for (int off = 128; off; off >>= 1) {
            if (tid < off) red[tid] = fmaxf(red[tid], red[tid + off]);
            __syncthreads();
        }
        if (tid == 0) pool[b * 14 + poff + o] = red[0];
        __syncthreads();
    }
}

__global__ void fc_kernel(const float* __restrict__ pool, const float* __restrict__ fw,
                          const float* __restrict__ fb, float* __restrict__ out)
{
    const int i = threadIdx.x;           // 256 = B*OUT
    const int b = i >> 1, o = i & 1;
    float acc = fb[o];
#pragma unroll
    for (int f = 0; f < 14; ++f) acc += pool[b * 14 + f] * fw[o * 14 + f];
    out[i] = acc;
}

// ---------------------------------------------------------------------------
extern "C" void kernel_launch(void* const* d_in, const int* in_sizes, int n_in,
                              void* d_out, int out_size, void* d_ws, size_t ws_size,
                              hipStream_t stream)
{
    const int*   utt    = (const int*)  d_in[0];
    const float* emb    = (const float*)d_in[2];
    const float* w_ih0  = (const float*)d_in[3];
    const float* w_hh0  = (const float*)d_in[4];
    const float* b_ih0  = (const float*)d_in[5];
    const float* b_hh0  = (const float*)d_in[6];
    const float* w_ih1  = (const float*)d_in[7];
    const float* w_hh1  = (const float*)d_in[8];
    const float* b_ih1  = (const float*)d_in[9];
    const float* b_hh1  = (const float*)d_in[10];
    const float* att_w  = (const float*)d_in[11];
    const float* att_b  = (const float*)d_in[12];
    const float* att_wv2= (const float*)d_in[13];
    const float* att_bv = (const float*)d_in[14];
    const float* att_wv1= (const float*)d_in[15];
    const float* fc_w   = (const float*)d_in[16];
    const float* fc_b   = (const float*)d_in[17];
    const float* cw[4] = {(const float*)d_in[18], (const float*)d_in[20],
                          (const float*)d_in[22], (const float*)d_in[24]};
    const float* cb[4] = {(const float*)d_in[19], (const float*)d_in[21],
                          (const float*)d_in[23], (const float*)d_in[25]};

    float* ws = (float*)d_ws;
    // fat layout: fp32 gx staging; slim: bf16 gx (proven in-bounds)
    const bool fat = ws_size >= (size_t)42895104 * 4;
    const size_t oH1 = fat ? 25165824u : 12582912u;   // gx region in f32 slots
    float* H1   = ws + oH1;            // 8,388,608 f ; later aliased as MATc
    float* H2   = H1 + 8388608;        // 8,388,608 f
    float* WP   = H2 + 8388608;        //    65,536 f
    float* S    = WP + 65536;          //   131,072 f
    float* Aa   = S + 131072;
    float* AL   = Aa + 131072;
    float* AAa  = AL + 131072;
    float* NEW_ = AAa + 131072;
    float* NWD  = NEW_ + 131072;       //    32,768 f
    float* POOL = NWD + 32768;         //     1,792 f
    float* MATc = H1;                  // alias (H1 dead after layer-1 gemm)
    float* XWT  = ws;                  // alias (gx dead after layer-1 scan)

    if (fat) {
        float* GX = ws;
        gemm_kernel<float, float, float, true, true, 0><<<dim3(12, 512), 256, 0, stream>>>(
            emb, w_ih0, b_ih0, GX, utt, BLn, 768, En);
        gru_scan<float><<<dim3(Bn, 2), 384, 0, stream>>>(GX, w_hh0, b_hh0, H1);
        gemm_kernel<float, float, float, true, false, 0><<<dim3(12, 512), 256, 0, stream>>>(
            H1, w_ih1, b_ih1, GX, nullptr, BLn, 768, Dn);
        gru_scan<float><<<dim3(Bn, 2), 384, 0, stream>>>(GX, w_hh1, b_hh1, H2);
    } else {
        bf16* GX = (bf16*)ws;
        gemm_kernel<float, float, bf16, true, true, 0><<<dim3(12, 512), 256, 0, stream>>>(
            emb, w_ih0, b_ih0, GX, utt, BLn, 768, En);
        gru_scan<bf16><<<dim3(Bn, 2), 384, 0, stream>>>(GX, w_hh0, b_hh0, H1);
        gemm_kernel<float, float, bf16, true, false, 0><<<dim3(12, 512), 256, 0, stream>>>(
            H1, w_ih1, b_ih1, GX, nullptr, BLn, 768, Dn);
        gru_scan<bf16><<<dim3(Bn, 2), 384, 0, stream>>>(GX, w_hh1, b_hh1, H2);
    }

    // attention: per channel, mat_c = x @ att_w[c] (reusing MATc), then scores
    for (int c = 0; c < 4; ++c) {
        gemm_kernel<float, float, float, false, false, 0><<<dim3(4, 512), 256, 0, stream>>>(
            H2, att_w + (size_t)c * Dn * Dn, (const float*)nullptr, MATc, nullptr, BLn, Dn, Dn);
        attn_score_kernel<<<dim3(4, Bn), 256, 0, stream>>>(H2, MATc, att_b, c, S + (size_t)c * 32768);
    }
    softmax256<<<Cn * Bn, 256, 0, stream>>>(S, Aa);

    attn_vec_kernel<<<dim3(BLn / 64, Cn), 256, 0, stream>>>(H2, att_wv2, att_bv, att_wv1, AL);
    softmax256<<<Cn * Bn, 256, 0, stream>>>(AL, AAa);
    weighted_sum_kernel<<<dim3(Bn, Cn), 256, 0, stream>>>(AAa, H2, NEW_);

    // conv stage via xw GEMM decomposition (Cf never materialized)
    wpack_fill<<<5, 256, 0, stream>>>(cw[0], cw[1], cw[2], cw[3], WP);
    gemm_kernel<float, float, float, true, false, 1><<<dim3(4, 512), 256, 0, stream>>>(
        H2, WP, (const float*)nullptr, XWT, nullptr, BLn, 256, 256);
    nwd_kernel<<<Bn, 256, 0, stream>>>(NEW_, WP, NWD);

    const int baserow[4] = {0, 16, 52, 116};
    const int poff[4]    = {0, 2, 5, 9};
    for (int f = 0; f < 4; ++f)
        conv_combine<<<Bn, 256, 0, stream>>>(XWT, Aa, NWD, cb[f], POOL, f + 2, baserow[f], poff[f]);

    fc_kernel<<<1, 256, 0, stream>>>(POOL, fc_w, fc_b, (float*)d_out);
}

// Round 5
// 1381.996 us; speedup vs baseline: 2.9106x; 2.0364x over previous
//
#include <hip/hip_runtime.h>
#include <hip/hip_bf16.h>

#define Bn  128
#define Ln  256
#define En  300
#define Hn  128
#define Cn  4
#define Dn  256     // 2H
#define G3n 384     // 3H
#define BLn (Bn * Ln)   // 32768

typedef __hip_bfloat16 bf16;
typedef short s16x8 __attribute__((ext_vector_type(8)));
typedef float f32x4 __attribute__((ext_vector_type(4)));

__device__ __forceinline__ float ldf(const float* p) { return *p; }
__device__ __forceinline__ float ldf(const bf16* p)  { return __bfloat162float(*p); }
__device__ __forceinline__ void stf(float* p, float v) { *p = v; }
__device__ __forceinline__ void stf(bf16* p, float v)  { *p = __float2bfloat16(v); }

__device__ __forceinline__ ushort f2bf(float f) {
    bf16 h = __float2bfloat16(f);
    return *reinterpret_cast<ushort*>(&h);
}

// ---------------------------------------------------------------------------
// MFMA bf16 GEMM: C[M,N] = A[M,K] * W^T + bias   (W is (N,K) row-major)
//   GATHER: A row m = A[gidx[m]*K ..]    SM==1: store C[(m>>8),n,(m&255)]
// 128x128 tile, 4 waves (2x2 of 64x64), BK=32, LDS rows padded to 40 bf16.
// fp32 loads are converted to bf16 during LDS staging (inputs are fp32).
// ---------------------------------------------------------------------------
template<class OT, bool GATHER, int SM>
__global__ __launch_bounds__(256)
void gemm_mfma(const float* __restrict__ A, const float* __restrict__ W,
               const float* __restrict__ bias, OT* __restrict__ Cout,
               const int* __restrict__ gidx, int M, int N, int K)
{
    __shared__ ushort Asm[128 * 40];
    __shared__ ushort Bsm[128 * 40];
    const int bm = blockIdx.y * 128, bn = blockIdx.x * 128;
    const int tid = threadIdx.x;
    const int lane = tid & 63, w = tid >> 6, wr = w >> 1, wc = w & 1;

    // hoisted staging row pointers (row index independent of k-step)
    const float* arow[4];
    const float* brow[4];
#pragma unroll
    for (int u = 0; u < 4; ++u) {
        const int idx = tid + u * 256;
        const int m = idx >> 3;
        arow[u] = A + (size_t)(GATHER ? gidx[bm + m] : (bm + m)) * K;
        brow[u] = W + (size_t)(bn + m) * K;
    }

    f32x4 acc[4][4] = {};
    const int nkt = (K + 31) >> 5;
    for (int kt = 0; kt < nkt; ++kt) {
        const int k0 = kt << 5;
#pragma unroll
        for (int u = 0; u < 4; ++u) {
            const int idx = tid + u * 256;
            const int m = idx >> 3, kq = idx & 7;
            const int kb = k0 + kq * 4;
            float4 v, q;
            if (kb + 4 <= K) {
                v = *(const float4*)(arow[u] + kb);
                q = *(const float4*)(brow[u] + kb);
            } else {
                v.x = kb + 0 < K ? arow[u][kb + 0] : 0.f;
                v.y = kb + 1 < K ? arow[u][kb + 1] : 0.f;
                v.z = kb + 2 < K ? arow[u][kb + 2] : 0.f;
                v.w = kb + 3 < K ? arow[u][kb + 3] : 0.f;
                q.x = kb + 0 < K ? brow[u][kb + 0] : 0.f;
                q.y = kb + 1 < K ? brow[u][kb + 1] : 0.f;
                q.z = kb + 2 < K ? brow[u][kb + 2] : 0.f;
                q.w = kb + 3 < K ? brow[u][kb + 3] : 0.f;
            }
            *(ushort4*)&Asm[m * 40 + kq * 4] =
                make_ushort4(f2bf(v.x), f2bf(v.y), f2bf(v.z), f2bf(v.w));
            *(ushort4*)&Bsm[m * 40 + kq * 4] =
                make_ushort4(f2bf(q.x), f2bf(q.y), f2bf(q.z), f2bf(q.w));
        }
        __syncthreads();
        s16x8 af[4], bfr[4];
#pragma unroll
        for (int t = 0; t < 4; ++t) {
            af[t]  = *(const s16x8*)&Asm[(wr * 64 + t * 16 + (lane & 15)) * 40 + (lane >> 4) * 8];
            bfr[t] = *(const s16x8*)&Bsm[(wc * 64 + t * 16 + (lane & 15)) * 40 + (lane >> 4) * 8];
        }
#pragma unroll
        for (int mf = 0; mf < 4; ++mf)
#pragma unroll
            for (int nf = 0; nf < 4; ++nf)
                acc[mf][nf] = __builtin_amdgcn_mfma_f32_16x16x32_bf16(
                    af[mf], bfr[nf], acc[mf][nf], 0, 0, 0);
        __syncthreads();
    }

#pragma unroll
    for (int mf = 0; mf < 4; ++mf)
#pragma unroll
        for (int nf = 0; nf < 4; ++nf) {
            const int col = bn + wc * 64 + nf * 16 + (lane & 15);
            const float bv_ = bias ? bias[col] : 0.f;
#pragma unroll
            for (int i = 0; i < 4; ++i) {
                const int row = bm + wr * 64 + mf * 16 + (lane >> 4) * 4 + i;
                const float v = acc[mf][nf][i] + bv_;
                if (SM == 1)
                    stf(&Cout[((size_t)(row >> 8) * N + col) * 256 + (row & 255)], v);
                else
                    stf(&Cout[(size_t)row * N + col], v);
            }
        }
}

// ---------------------------------------------------------------------------
// attn score, MFMA: s[b,i] = sum_j tanh( x_b[i,:]·mat_b[j,:] + att_b[c] )
// block = (i-tile of 128, b); waves own 32 rows each; j tiled 2x128;
// M never materialized; row-sum reduced via shfl within 16-lane groups.
// ---------------------------------------------------------------------------
__global__ __launch_bounds__(256)
void attn_score_mfma(const float* __restrict__ x, const float* __restrict__ matc,
                     const float* __restrict__ attb, int c, float* __restrict__ sout)
{
    const int it = blockIdx.x, b = blockIdx.y;
    const float* A  = x    + ((size_t)b * 256 + it * 128) * 256;
    const float* Bm = matc + (size_t)b * 65536;
    __shared__ ushort Xs[128 * 40];
    __shared__ ushort Ms[128 * 40];
    const int tid = threadIdx.x, lane = tid & 63, w = tid >> 6;
    const float bc = attb[c];
    float psum[2][4] = {};

    for (int jt = 0; jt < 2; ++jt) {
        f32x4 acc[2][8] = {};
        for (int kt = 0; kt < 8; ++kt) {
            const int k0 = kt << 5;
#pragma unroll
            for (int u = 0; u < 4; ++u) {
                const int idx = tid + u * 256;
                const int m = idx >> 3, kq = idx & 7;
                const float4 v = *(const float4*)(A + (size_t)m * 256 + k0 + kq * 4);
                const float4 q = *(const float4*)(Bm + (size_t)(jt * 128 + m) * 256 + k0 + kq * 4);
                *(ushort4*)&Xs[m * 40 + kq * 4] =
                    make_ushort4(f2bf(v.x), f2bf(v.y), f2bf(v.z), f2bf(v.w));
                *(ushort4*)&Ms[m * 40 + kq * 4] =
                    make_ushort4(f2bf(q.x), f2bf(q.y), f2bf(q.z), f2bf(q.w));
            }
            __syncthreads();
            s16x8 af[2], bfr[8];
#pragma unroll
            for (int t = 0; t < 2; ++t)
                af[t] = *(const s16x8*)&Xs[(w * 32 + t * 16 + (lane & 15)) * 40 + (lane >> 4) * 8];
#pragma unroll
            for (int t = 0; t < 8; ++t)
                bfr[t] = *(const s16x8*)&Ms[(t * 16 + (lane & 15)) * 40 + (lane >> 4) * 8];
#pragma unroll
            for (int mf = 0; mf < 2; ++mf)
#pragma unroll
                for (int nf = 0; nf < 8; ++nf)
                    acc[mf][nf] = __builtin_amdgcn_mfma_f32_16x16x32_bf16(
                        af[mf], bfr[nf], acc[mf][nf], 0, 0, 0);
            __syncthreads();
        }
#pragma unroll
        for (int mf = 0; mf < 2; ++mf)
#pragma unroll
            for (int nf = 0; nf < 8; ++nf)
#pragma unroll
                for (int i = 0; i < 4; ++i)
                    psum[mf][i] += tanhf(acc[mf][nf][i] + bc);
    }

#pragma unroll
    for (int mf = 0; mf < 2; ++mf)
#pragma unroll
        for (int i = 0; i < 4; ++i) {
            float v = psum[mf][i];
            v += __shfl_xor(v, 1); v += __shfl_xor(v, 2);
            v += __shfl_xor(v, 4); v += __shfl_xor(v, 8);
            if ((lane & 15) == 0)
                sout[b * 256 + it * 128 + w * 32 + mf * 16 + (lane >> 4) * 4 + i] = v;
        }
}

// al[row] = sum_e sigmoid(gv[row,e] + bv[e]) * wv1[e]   (one wave per row)
__global__ __launch_bounds__(256)
void gv_reduce(const float* __restrict__ gv, const float* __restrict__ bv,
               const float* __restrict__ wv1, float* __restrict__ al)
{
    const int row = blockIdx.x * 4 + (threadIdx.x >> 6);
    const int l = threadIdx.x & 63;
    const float4 v  = *(const float4*)(gv + (size_t)row * 256 + l * 4);
    const float4 bb = *(const float4*)(bv + l * 4);
    const float4 w  = *(const float4*)(wv1 + l * 4);
    float s = w.x / (1.f + expf(-(v.x + bb.x)))
            + w.y / (1.f + expf(-(v.y + bb.y)))
            + w.z / (1.f + expf(-(v.z + bb.z)))
            + w.w / (1.f + expf(-(v.w + bb.w)));
#pragma unroll
    for (int m = 1; m < 64; m <<= 1) s += __shfl_xor(s, m);
    if (l == 0) al[row] = s;
}

// transpose 4 matrices of 256x256 (src[c][d][e] -> dst[c][e][d])
__global__ void transpose256(const float* __restrict__ src, float* __restrict__ dst)
{
    const float* s = src + (size_t)blockIdx.x * 65536;
    float* d = dst + (size_t)blockIdx.x * 65536;
    __shared__ float t[32][33];
    const int tx = threadIdx.x & 31, ty8 = threadIdx.x >> 5;
    for (int bi = 0; bi < 8; ++bi)
        for (int bj = 0; bj < 8; ++bj) {
            __syncthreads();
            for (int r = ty8; r < 32; r += 8)
                t[r][tx] = s[(size_t)(bi * 32 + r) * 256 + bj * 32 + tx];
            __syncthreads();
            for (int r = ty8; r < 32; r += 8)
                d[(size_t)(bj * 32 + r) * 256 + bi * 32 + tx] = t[tx][r];
        }
}

// ---------------------------------------------------------------------------
// GRU scan, register-resident weights (round-4: removed L2-BW bottleneck).
// ---------------------------------------------------------------------------
template<class GxT>
__global__ __launch_bounds__(384, 1)
void gru_scan(const GxT* __restrict__ gx, const float* __restrict__ w_hh,
              const float* __restrict__ b_hh, float* __restrict__ out)
{
    const int b = blockIdx.x, dir = blockIdx.y;
    const int r = threadIdx.x;
    __shared__ __align__(16) float h_sh[Hn];
    __shared__ float pre_rz[2 * Hn];
    __shared__ float gxn[Hn], ghn[Hn];

    const float* wrow = w_hh + ((size_t)dir * G3n + r) * Hn;
    float wreg[Hn];
#pragma unroll
    for (int j = 0; j < Hn / 4; ++j)
        *(float4*)(wreg + 4 * j) = *(const float4*)(wrow + 4 * j);
    const float bh = b_hh[dir * G3n + r];

    if (r < Hn) h_sh[r] = 0.f;
    __syncthreads();

    const size_t gbase = (size_t)b * Ln * 768 + dir * G3n + r;
    const long   gstep = dir ? -768 : 768;
    const size_t g0    = dir ? (gbase + (size_t)(Ln - 1) * 768) : gbase;

    float gcur = ldf(&gx[g0]);
    float gnx  = ldf(&gx[g0 + gstep]);

    for (int s = 0; s < Ln; ++s) {
        const int t = dir ? (Ln - 1 - s) : s;
        float gn2 = 0.f;
        if (s + 2 < Ln) gn2 = ldf(&gx[g0 + (long)(s + 2) * gstep]);

        float a0 = 0.f, a1 = 0.f, a2 = 0.f, a3 = 0.f;
#pragma unroll
        for (int j = 0; j < Hn / 4; ++j) {
            const float4 hv = *(const float4*)(h_sh + 4 * j);
            a0 = fmaf(wreg[4 * j + 0], hv.x, a0);
            a1 = fmaf(wreg[4 * j + 1], hv.y, a1);
            a2 = fmaf(wreg[4 * j + 2], hv.z, a2);
            a3 = fmaf(wreg[4 * j + 3], hv.w, a3);
        }
        const float acc = (a0 + a1) + (a2 + a3) + bh;
        const float gxv = gcur;
        if (r < 2 * Hn) pre_rz[r] = gxv + acc;
        else { gxn[r - 2 * Hn] = gxv; ghn[r - 2 * Hn] = acc; }
        __syncthreads();
        if (r < Hn) {
            const float rr = 1.f / (1.f + expf(-pre_rz[r]));
            const float zz = 1.f / (1.f + expf(-pre_rz[Hn + r]));
            const float nn = tanhf(gxn[r] + rr * ghn[r]);
            const float hnew = (1.f - zz) * nn + zz * h_sh[r];
            h_sh[r] = hnew;
            out[((size_t)b * Ln + t) * Dn + dir * Hn + r] = hnew;
        }
        __syncthreads();
        gcur = gnx;
        gnx  = gn2;
    }
}

__global__ void softmax256(const float* __restrict__ in, float* __restrict__ out)
{
    __shared__ float red[256];
    const int row = blockIdx.x, t = threadIdx.x;
    const float v = in[(size_t)row * 256 + t];
    red[t] = v; __syncthreads();
    for (int off = 128; off; off >>= 1) {
        if (t < off) red[t] = fmaxf(red[t], red[t + off]);
        __syncthreads();
    }
    const float mx = red[0]; __syncthreads();
    const float e = expf(v - mx);
    red[t] = e; __syncthreads();
    for (int off = 128; off; off >>= 1) {
        if (t < off) red[t] += red[t + off];
        __syncthreads();
    }
    out[(size_t)row * 256 + t] = e / red[0];
}

// new[c,b,d] = sum_l aa[c,b,l] * x[b,l,d]
__global__ void weighted_sum_kernel(const float* __restrict__ aa,
                                    const float* __restrict__ x,
                                    float* __restrict__ outnew)
{
    const int b = blockIdx.x, c = blockIdx.y, d = threadIdx.x;
    __shared__ float w[Ln];
    w[d] = aa[((size_t)c * Bn + b) * Ln + d];
    __syncthreads();
    float acc = 0.f;
    for (int l = 0; l < Ln; ++l)
        acc += w[l] * x[((size_t)b * Ln + l) * Dn + d];
    outnew[((size_t)c * Bn + b) * Dn + d] = acc;
}

// pack conv filter rows (216) into 256x256 fp32 (rows 216+ zero)
__global__ void wpack_fill(const float* __restrict__ w0, const float* __restrict__ w1,
                           const float* __restrict__ w2, const float* __restrict__ w3,
                           float* __restrict__ wp)
{
    const int f = blockIdx.x;
    if (f < 4) {
        const int cnt[4]  = {4096, 9216, 16384, 25600};
        const int boff[4] = {0, 4096, 13312, 29696};
        const float* src = f == 0 ? w0 : f == 1 ? w1 : f == 2 ? w2 : w3;
        for (int i = threadIdx.x; i < cnt[f]; i += blockDim.x)
            wp[boff[f] + i] = src[i];
    } else {
        for (int i = threadIdx.x; i < 65536 - 55296; i += blockDim.x)
            wp[55296 + i] = 0.f;
    }
}

// nwd[b,row] = dot(new[c_of_row, b, :], wpack[row, :])
__global__ __launch_bounds__(256)
void nwd_kernel(const float* __restrict__ nw, const float* __restrict__ wp,
                float* __restrict__ nwd)
{
    const int b = blockIdx.x;
    __shared__ float ns[4][256];
    for (int i = threadIdx.x; i < 1024; i += 256)
        ns[i >> 8][i & 255] = nw[((size_t)((i >> 8) * Bn + b) << 8) + (i & 255)];
    __syncthreads();
    const int row = threadIdx.x;
    if (row < 216) {
        int f, base;
        if (row < 16)       { f = 0; base = 0; }
        else if (row < 52)  { f = 1; base = 16; }
        else if (row < 116) { f = 2; base = 52; }
        else                { f = 3; base = 116; }
        const int fs = f + 2, local = row - base;
        const int c = (local / fs) & 3;
        const float* wr = wp + (size_t)row * 256;
        float acc = 0.f;
        for (int k = 0; k < 256; ++k) acc += ns[c][k] * wr[k];
        nwd[b * 256 + row] = acc;
    }
}

// conv+relu+maxpool via decomposition over a-weighted x rows + new offset
__global__ __launch_bounds__(256)
void conv_combine(const float* __restrict__ xwT, const float* __restrict__ a,
                  const float* __restrict__ nwd, const float* __restrict__ cb,
                  float* __restrict__ pool, int fs, int base, int poff)
{
    const int b = blockIdx.x, tid = threadIdx.x;
    __shared__ float ash[4][256];
    __shared__ float basev[5];
    __shared__ float red[256];
    for (int i = tid; i < 1024; i += 256)
        ash[i >> 8][i & 255] = a[((size_t)((i >> 8) * Bn + b) << 8) + (i & 255)];
    if (tid < fs) {
        float s = cb[tid];
        for (int c = 0; c < 4; ++c)
            for (int kh = 0; kh < fs; ++kh)
                s += nwd[b * 256 + base + (tid * 4 + c) * fs + kh];
        basev[tid] = s;
    }
    __syncthreads();
    const int ni = Ln - fs + 1;
    const float* xb = xwT + ((size_t)b << 16);
    for (int o = 0; o < fs; ++o) {
        float best = 0.f;
        if (tid < ni) {
            float acc = basev[o];
            for (int c = 0; c < 4; ++c)
                for (int kh = 0; kh < fs; ++kh) {
                    const int row = base + (o * 4 + c) * fs + kh;
                    acc += ash[c][tid + kh] * xb[(row << 8) + tid + kh];
                }
            best = fmaxf(acc, 0.f);
        }
        red[tid] = best; __syncthreads();
        for (int off = 128; off; off >>= 1) {
            if (tid < off) red[tid] = fmaxf(red[tid], red[tid + off]);
            __syncthreads();
        }
        if (tid == 0) pool[b * 14 + poff + o] = red[0];
        __syncthreads();
    }
}

__global__ void fc_kernel(const float* __restrict__ pool, const float* __restrict__ fw,
                          const float* __restrict__ fb, float* __restrict__ out)
{
    const int i = threadIdx.x;           // 256 = B*OUT
    const int b = i >> 1, o = i & 1;
    float acc = fb[o];
#pragma unroll
    for (int f = 0; f < 14; ++f) acc += pool[b * 14 + f] * fw[o * 14 + f];
    out[i] = acc;
}

// ---------------------------------------------------------------------------
extern "C" void kernel_launch(void* const* d_in, const int* in_sizes, int n_in,
                              void* d_out, int out_size, void* d_ws, size_t ws_size,
                              hipStream_t stream)
{
    const int*   utt    = (const int*)  d_in[0];
    const float* emb    = (const float*)d_in[2];
    const float* w_ih0  = (const float*)d_in[3];
    const float* w_hh0  = (const float*)d_in[4];
    const float* b_ih0  = (const float*)d_in[5];
    const float* b_hh0  = (const float*)d_in[6];
    const float* w_ih1  = (const float*)d_in[7];
    const float* w_hh1  = (const float*)d_in[8];
    const float* b_ih1  = (const float*)d_in[9];
    const float* b_hh1  = (const float*)d_in[10];
    const float* att_w  = (const float*)d_in[11];
    const float* att_b  = (const float*)d_in[12];
    const float* att_wv2= (const float*)d_in[13];
    const float* att_bv = (const float*)d_in[14];
    const float* att_wv1= (const float*)d_in[15];
    const float* fc_w   = (const float*)d_in[16];
    const float* fc_b   = (const float*)d_in[17];
    const float* cw[4] = {(const float*)d_in[18], (const float*)d_in[20],
                          (const float*)d_in[22], (const float*)d_in[24]};
    const float* cb[4] = {(const float*)d_in[19], (const float*)d_in[21],
                          (const float*)d_in[23], (const float*)d_in[25]};

    float* ws = (float*)d_ws;
    // layout (f32 slots), extent ~121.5 MB (round-2/3 proved ~121.3 safe)
    bf16*  GX   = (bf16*)ws;           // 32768*768 bf16 = 12,582,912 f32 slots
    float* H1   = ws + 12582912;       // 8,388,608 f ; later aliased as MATc
    float* H2   = H1 + 8388608;        // 8,388,608 f
    float* WT   = H2 + 8388608;        //   262,144 f (att_wT, then wv2T)
    float* WP   = WT + 262144;         //    65,536 f
    float* S    = WP + 65536;          //   131,072 f
    float* Aa   = S + 131072;
    float* AL   = Aa + 131072;
    float* AAa  = AL + 131072;
    float* NEW_ = AAa + 131072;
    float* NWD  = NEW_ + 131072;       //    32,768 f
    float* POOL = NWD + 32768;         //     1,792 f
    float* MATc = H1;                  // alias (H1 dead after layer-1 gemm)
    float* GV   = ws;                  // alias gx region (dead after scan 2)
    float* XWT  = ws;                  // alias (GV dead after gv_reduce)

    // layer 0 + scan
    gemm_mfma<bf16, true, 0><<<dim3(6, 256), 256, 0, stream>>>(
        emb, w_ih0, b_ih0, GX, utt, BLn, 768, En);
    gru_scan<bf16><<<dim3(Bn, 2), 384, 0, stream>>>(GX, w_hh0, b_hh0, H1);
    // layer 1 + scan
    gemm_mfma<bf16, false, 0><<<dim3(6, 256), 256, 0, stream>>>(
        H1, w_ih1, b_ih1, GX, nullptr, BLn, 768, Dn);
    gru_scan<bf16><<<dim3(Bn, 2), 384, 0, stream>>>(GX, w_hh1, b_hh1, H2);

    // scalar attention: mat_c = x @ att_w[c], fused tanh-sum scores
    transpose256<<<4, 256, 0, stream>>>(att_w, WT);
    for (int c = 0; c < 4; ++c) {
        gemm_mfma<float, false, 0><<<dim3(2, 256), 256, 0, stream>>>(
            H2, WT + (size_t)c * 65536, nullptr, MATc, nullptr, BLn, Dn, Dn);
        attn_score_mfma<<<dim3(2, Bn), 256, 0, stream>>>(
            H2, MATc, att_b, c, S + (size_t)c * 32768);
    }
    softmax256<<<Cn * Bn, 256, 0, stream>>>(S, Aa);

    // vector attention: gv = x @ wv2[c], reduce with sigmoid*wv1
    transpose256<<<4, 256, 0, stream>>>(att_wv2, WT);
    for (int c = 0; c < 4; ++c) {
        gemm_mfma<float, false, 0><<<dim3(2, 256), 256, 0, stream>>>(
            H2, WT + (size_t)c * 65536, nullptr, GV, nullptr, BLn, Dn, Dn);
        gv_reduce<<<BLn / 4, 256, 0, stream>>>(
            GV, att_bv + c * Dn, att_wv1 + c * Dn, AL + (size_t)c * BLn);
    }
    softmax256<<<Cn * Bn, 256, 0, stream>>>(AL, AAa);
    weighted_sum_kernel<<<dim3(Bn, Cn), 256, 0, stream>>>(AAa, H2, NEW_);

    // conv stage via xw GEMM decomposition (Cf never materialized)
    wpack_fill<<<5, 256, 0, stream>>>(cw[0], cw[1], cw[2], cw[3], WP);
    gemm_mfma<float, false, 1><<<dim3(2, 256), 256, 0, stream>>>(
        H2, WP, nullptr, XWT, nullptr, BLn, Dn, Dn);
    nwd_kernel<<<Bn, 256, 0, stream>>>(NEW_, WP, NWD);

    const int baserow[4] = {0, 16, 52, 116};
    const int poff[4]    = {0, 2, 5, 9};
    for (int f = 0; f < 4; ++f)
        conv_combine<<<Bn, 256, 0, stream>>>(XWT, Aa, NWD, cb[f], POOL, f + 2, baserow[f], poff[f]);

    fc_kernel<<<1, 256, 0, stream>>>(POOL, fc_w, fc_b, (float*)d_out);
}